// Round 6
// baseline (801.960 us; speedup 1.0000x reference)
//
#include <hip/hip_runtime.h>
#include <math.h>

// B=2,H=16,S=2048,D=64 fp32 attention, outputs (O, P). MFMA bf16.
// 2048 blocks x 4 waves; block = fold-pair (16-row groups g and 127-g),
// each group's K-range split across 2 waves. Low-VGPR variant: rely on
// 8 blocks/CU (32 waves/CU) TLP instead of register pipelining.
#define NB 2
#define NH 16
#define SL 2048
#define DD 64
#define KC 64
#define NCH (SL / KC)
#define NT 256
#define LPS 68           // slab fp32 row stride (pad +4)

typedef short bf16x8 __attribute__((ext_vector_type(8)));
typedef float f32x4  __attribute__((ext_vector_type(4)));

__device__ __forceinline__ unsigned short f2bf(float x) {
    unsigned u = __float_as_uint(x);
    u += 0x7fffu + ((u >> 16) & 1u);     // round-to-nearest-even
    return (unsigned short)(u >> 16);
}

// LDS-only barrier: waits local ops, leaves global stores in flight.
__device__ __forceinline__ void lds_barrier() {
    asm volatile("s_waitcnt lgkmcnt(0)\n\ts_barrier" ::: "memory");
}

// ---------------- prep: fp32 -> bf16 elementwise (Q scaled, K raw) -----------
__global__ __launch_bounds__(256)
void cvt_bf16(const float* __restrict__ in, unsigned short* __restrict__ out,
              int n4, float scale)
{
    int i = blockIdx.x * 256 + threadIdx.x;
    if (i >= n4) return;
    float4 v = ((const float4*)in)[i];
    ushort4 o;
    o.x = f2bf(v.x * scale); o.y = f2bf(v.y * scale);
    o.z = f2bf(v.z * scale); o.w = f2bf(v.w * scale);
    ((ushort4*)out)[i] = o;
}

// ---------------- prep: V[bh][s][d] fp32 -> Vt[bh][d][s] bf16 ----------------
__global__ __launch_bounds__(256)
void transpose_v(const float* __restrict__ V, unsigned short* __restrict__ Vt)
{
    __shared__ __align__(16) unsigned short vt[64 * 72];  // [d][r], stride 72
    const int bh = blockIdx.x >> 5;
    const int s0 = (blockIdx.x & 31) * 64;
    const int t  = threadIdx.x;

    const float4* src = (const float4*)(V + ((size_t)bh * SL + s0) * DD);
    #pragma unroll
    for (int i = 0; i < 4; ++i) {
        int idx = t + i * 256;
        int r = idx >> 4, d4 = idx & 15;
        float4 v = src[r * 16 + d4];
        vt[(d4 * 4 + 0) * 72 + r] = f2bf(v.x);
        vt[(d4 * 4 + 1) * 72 + r] = f2bf(v.y);
        vt[(d4 * 4 + 2) * 72 + r] = f2bf(v.z);
        vt[(d4 * 4 + 3) * 72 + r] = f2bf(v.w);
    }
    __syncthreads();
    const int d = t >> 2, seg = t & 3;
    unsigned short* dst = Vt + ((size_t)bh * DD + d) * SL + s0 + seg * 16;
    uint4 p0 = *(const uint4*)&vt[d * 72 + seg * 16];
    uint4 p1 = *(const uint4*)&vt[d * 72 + seg * 16 + 8];
    *(uint4*)dst = p0;
    *(uint4*)(dst + 8) = p1;
}

// ---------------- main fused attention ---------------------------------------
__global__ __launch_bounds__(NT, 8)   // force VGPR<=64: 8 blocks/CU, 32 waves/CU
void attn_mfma(const unsigned short* __restrict__ Qb,
               const unsigned short* __restrict__ Kb,
               const unsigned short* __restrict__ Vt,
               const float* __restrict__ Mg,
               const int* __restrict__ MNg,
               float* __restrict__ Og)
{
    // Per-ROLE slab (wave-private during Phase B; shared only at combines).
    __shared__ __align__(16) float ps[4][16 * LPS];
    __shared__ float lsx[4][16];

    const int tid  = threadIdx.x;
    const int w    = tid >> 6;
    const int lane = tid & 63;
    const int l15  = lane & 15;
    const int qd   = lane >> 4;

    // 2048 blocks: xcd = lin&7 (HW RR), 256 per XCD covering 4 bh x 64 pairs.
    const int lin  = blockIdx.x;
    const int xcd  = lin & 7;
    const int iloc = lin >> 3;          // 0..255
    const int bh   = xcd * 4 + (iloc >> 6);
    const int g    = iloc & 63;         // fold-pair id (groups g and 127-g)
    const int j    = (iloc >> 5) & 7;   // varies across blocks on same CU slot
    const int b    = bh >> 4;

    // role 0,1: low group k-halves; role 2,3: high group k-halves.
    const int role  = (w + j) & 3;
    const int khalf = role & 1;
    const int r0    = (role < 2) ? g * 16 : 2032 - g * 16;

    const int diag = (MNg[0] != 0) ? -1 : 0;

    // Rows owned by this lane: r0 + qd*4 + reg.  rlim<0 <=> degenerate row.
    int rlim[4]; int anyDeg = 0;
    #pragma unroll
    for (int reg = 0; reg < 4; ++reg) {
        int row = r0 + qd * 4 + reg;
        float m = Mg[(size_t)b * SL + row];
        int rl = row + diag;
        if (m == 0.0f) rl = -1;
        rlim[reg] = rl;
        anyDeg |= (rl < 0);
    }
    const bool grpDeg = __any(anyDeg);          // same for both partner waves
    const int lastB = grpDeg ? (NCH - 1) : ((r0 + 15 + diag) >> 6);
    const int N     = lastB + 1;                // compute chunks for this group
    const int kcMid = N >> 1;
    const int kcBeg = khalf ? kcMid : 0;
    const int kcEnd = khalf ? N : kcMid;

    const unsigned short* Qh  = Qb + (size_t)bh * SL * DD;
    const unsigned short* Kh  = Kb + (size_t)bh * SL * DD;
    const unsigned short* Vth = Vt + (size_t)bh * DD * SL;
    float* Oo   = Og + ((size_t)bh * SL + r0) * DD;
    float* Sout = Og + (size_t)NB * NH * SL * DD
                     + (size_t)bh * SL * SL + (size_t)r0 * SL;
    float* slab = ps[role];

    // Q A-frags (persistent). Q pre-scaled by 0.125*log2(e): P = exp2(acc).
    const unsigned short* qrow = Qh + (size_t)(r0 + l15) * DD + qd * 8;
    bf16x8 qf0 = *(const bf16x8*)qrow;
    bf16x8 qf1 = *(const bf16x8*)(qrow + 32);

    // ---------------- Phase A: partial row sums over [kcBeg, kcEnd) ----------
    // Minimal register footprint: per-tile load straight into MFMA; latency
    // hidden by 8 waves/SIMD TLP, not by register pipelines.
    float lacc[4] = {0.0f, 0.0f, 0.0f, 0.0f};
    for (int it = kcBeg * 4; it < kcEnd * 4; ++it) {
        const unsigned short* kr = Kh + (size_t)(it * 16 + l15) * DD + qd * 8;
        bf16x8 f0 = *(const bf16x8*)kr;
        bf16x8 f1 = *(const bf16x8*)(kr + 32);
        f32x4 acc = {0.0f, 0.0f, 0.0f, 0.0f};
        __builtin_amdgcn_s_setprio(1);
        acc = __builtin_amdgcn_mfma_f32_16x16x32_bf16(qf0, f0, acc, 0, 0, 0);
        acc = __builtin_amdgcn_mfma_f32_16x16x32_bf16(qf1, f1, acc, 0, 0, 0);
        __builtin_amdgcn_s_setprio(0);
        const int col = it * 16 + l15;
        #pragma unroll
        for (int reg = 0; reg < 4; ++reg)
            lacc[reg] += (col <= rlim[reg]) ? __builtin_exp2f(acc[reg]) : 0.0f;
    }

    // Intra-wave reduce over l15, then cross-wave combine with k-half partner.
    float lsum[4];
    #pragma unroll
    for (int reg = 0; reg < 4; ++reg) {
        float s = lacc[reg];
        s += __shfl_xor(s, 1);  s += __shfl_xor(s, 2);
        s += __shfl_xor(s, 4);  s += __shfl_xor(s, 8);
        lsum[reg] = s;
    }
    if (l15 == 0) {
        #pragma unroll
        for (int reg = 0; reg < 4; ++reg)
            lsx[role][qd * 4 + reg] = lsum[reg];
    }
    lds_barrier();
    float pmul[4], pfill[4];
    #pragma unroll
    for (int reg = 0; reg < 4; ++reg) {
        float tot = lsum[reg] + lsx[role ^ 1][qd * 4 + reg];
        pmul[reg]  = (rlim[reg] < 0) ? 0.0f : 1.0f / tot;
        pfill[reg] = (rlim[reg] < 0) ? (1.0f / (float)SL) : 0.0f;
    }

    // ---------------- Phase B: emit P, accumulate partial O ------------------
    f32x4 oacc[4];
    #pragma unroll
    for (int nt = 0; nt < 4; ++nt) oacc[nt] = (f32x4){0.0f, 0.0f, 0.0f, 0.0f};

    for (int kc = kcBeg; kc < kcEnd; ++kc) {
        const int c0 = kc * KC;
        #pragma unroll
        for (int nt = 0; nt < 4; ++nt) {
            const unsigned short* kr = Kh + (size_t)(c0 + nt * 16 + l15) * DD + qd * 8;
            bf16x8 f0 = *(const bf16x8*)kr;
            bf16x8 f1 = *(const bf16x8*)(kr + 32);
            f32x4 acc = {0.0f, 0.0f, 0.0f, 0.0f};
            __builtin_amdgcn_s_setprio(1);
            acc = __builtin_amdgcn_mfma_f32_16x16x32_bf16(qf0, f0, acc, 0, 0, 0);
            acc = __builtin_amdgcn_mfma_f32_16x16x32_bf16(qf1, f1, acc, 0, 0, 0);
            __builtin_amdgcn_s_setprio(0);
            const int col = c0 + nt * 16 + l15;
            #pragma unroll
            for (int reg = 0; reg < 4; ++reg) {
                float val = (col <= rlim[reg]) ? __builtin_exp2f(acc[reg]) * pmul[reg]
                                               : pfill[reg];
                slab[(qd * 4 + reg) * LPS + nt * 16 + l15] = val;
            }
        }
        // Coalesced P store from wave-local slab (same-wave lgkm ordering).
        #pragma unroll
        for (int ii = 0; ii < 4; ++ii) {
            int idx = ii * 64 + lane;
            int rr = idx >> 4, c4 = idx & 15;
            *(float4*)(Sout + (size_t)rr * SL + c0 + c4 * 4) =
                *(const float4*)&slab[rr * LPS + c4 * 4];
        }
        // PV: A-frags from slab (fp32 -> bf16), V loaded per nt.
        bf16x8 paf[2];
        #pragma unroll
        for (int kb = 0; kb < 2; ++kb) {
            const float* pr = &slab[l15 * LPS + kb * 32 + qd * 8];
            float4 x = *(const float4*)pr;
            float4 y = *(const float4*)(pr + 4);
            bf16x8 f;
            f[0] = (short)f2bf(x.x); f[1] = (short)f2bf(x.y);
            f[2] = (short)f2bf(x.z); f[3] = (short)f2bf(x.w);
            f[4] = (short)f2bf(y.x); f[5] = (short)f2bf(y.y);
            f[6] = (short)f2bf(y.z); f[7] = (short)f2bf(y.w);
            paf[kb] = f;
        }
        #pragma unroll
        for (int nt = 0; nt < 4; ++nt) {
            const unsigned short* vr = Vth + (size_t)(nt * 16 + l15) * SL + c0 + qd * 8;
            bf16x8 v0 = *(const bf16x8*)vr;
            bf16x8 v1 = *(const bf16x8*)(vr + 32);
            __builtin_amdgcn_s_setprio(1);
            oacc[nt] = __builtin_amdgcn_mfma_f32_16x16x32_bf16(paf[0], v0, oacc[nt], 0, 0, 0);
            oacc[nt] = __builtin_amdgcn_mfma_f32_16x16x32_bf16(paf[1], v1, oacc[nt], 0, 0, 0);
            __builtin_amdgcn_s_setprio(0);
        }
    }

    // Zero region: rows split by khalf, each row zeroed DENSELY (contiguous
    // 1KB per store inst) from col N*64 to 2048 -> DRAM-friendly addresses.
    {
        const int zc0 = N * KC;              // ==2048 when deg -> loop skipped
        const int rbeg = khalf * 8;
        float4 z = make_float4(0.0f, 0.0f, 0.0f, 0.0f);
        for (int rr = rbeg; rr < rbeg + 8; ++rr) {
            float* rowp = Sout + (size_t)rr * SL;
            for (int c = zc0 + (lane << 2); c < SL; c += 256)
                *(float4*)(rowp + c) = z;
        }
    }

    // ---------------- O: combine partner halves via LDS, coalesced store -----
    #pragma unroll
    for (int nt = 0; nt < 4; ++nt)
        #pragma unroll
        for (int reg = 0; reg < 4; ++reg)
            slab[(qd * 4 + reg) * LPS + nt * 16 + l15] = oacc[nt][reg];
    lds_barrier();
    {
        const float* sA = ps[role & ~1];
        const float* sB = ps[role | 1];
        #pragma unroll
        for (int ii = 0; ii < 2; ++ii) {
            int idx = ii * 64 + lane;
            int rr = (idx >> 4) + khalf * 8;    // this wave stores 8 rows
            int c4 = idx & 15;
            float4 a = *(const float4*)&sA[rr * LPS + c4 * 4];
            float4 bv = *(const float4*)&sB[rr * LPS + c4 * 4];
            float4 o = make_float4(a.x + bv.x, a.y + bv.y, a.z + bv.z, a.w + bv.w);
            *(float4*)(Oo + (size_t)rr * DD + c4 * 4) = o;
        }
    }
}

extern "C" void kernel_launch(void* const* d_in, const int* in_sizes, int n_in,
                              void* d_out, int out_size, void* d_ws, size_t ws_size,
                              hipStream_t stream)
{
    const float* q  = (const float*)d_in[0];
    const float* k  = (const float*)d_in[1];
    const float* v  = (const float*)d_in[2];
    const float* mk = (const float*)d_in[3];
    const int*   mn = (const int*)d_in[4];
    float* out = (float*)d_out;

    const size_t nElem = (size_t)NB * NH * SL * DD;   // 4,194,304
    unsigned short* Qb = (unsigned short*)d_ws;
    unsigned short* Kp = Qb + nElem;
    unsigned short* Vp = Kp + nElem;

    const int n4 = (int)(nElem / 4);
    // Q pre-scaled by (1/8)*log2(e): QK^T lands directly in exp2 domain.
    cvt_bf16<<<n4 / 256, 256, 0, stream>>>(q, Qb, n4, 0.125f * 1.44269504f);
    cvt_bf16<<<n4 / 256, 256, 0, stream>>>(k, Kp, n4, 1.0f);
    transpose_v<<<NB * NH * (SL / 64), 256, 0, stream>>>(v, Vp);

    // 2048 blocks: 8 XCD x (4 bh x 64 fold-pairs) -> 8 blocks/CU target.
    attn_mfma<<<2048, NT, 0, stream>>>(Qb, Kp, Vp, mk, mn, out);
}

// Round 8
// 735.568 us; speedup vs baseline: 1.0903x; 1.0903x over previous
//
#include <hip/hip_runtime.h>
#include <math.h>

// B=2,H=16,S=2048,D=64 fp32 attention, outputs (O, P). MFMA bf16.
// 1024 blocks; block = fold-pair of 32-row groups (g, 63-g), two sweeps.
// Key change: P staged in a 32x256 LDS slab and stored as 1KB-contiguous
// runs per row (was 256B @ 8KB stride) -> DRAM write-locality fix.
#define NB 2
#define NH 16
#define SL 2048
#define DD 64
#define NT 256
#define SLABW 268        // slab fp32 row stride (256 + 12: bank-spread, 16B-aligned)

typedef short bf16x8 __attribute__((ext_vector_type(8)));
typedef float f32x4  __attribute__((ext_vector_type(4)));

__device__ __forceinline__ unsigned short f2bf(float x) {
    unsigned u = __float_as_uint(x);
    u += 0x7fffu + ((u >> 16) & 1u);     // round-to-nearest-even
    return (unsigned short)(u >> 16);
}

// LDS-only barrier: waits local ops, leaves global stores in flight.
__device__ __forceinline__ void lds_barrier() {
    asm volatile("s_waitcnt lgkmcnt(0)\n\ts_barrier" ::: "memory");
}

// ---------------- prep: fp32 -> bf16 elementwise (Q scaled, K raw) -----------
__global__ __launch_bounds__(256)
void cvt_bf16(const float* __restrict__ in, unsigned short* __restrict__ out,
              int n4, float scale)
{
    int i = blockIdx.x * 256 + threadIdx.x;
    if (i >= n4) return;
    float4 v = ((const float4*)in)[i];
    ushort4 o;
    o.x = f2bf(v.x * scale); o.y = f2bf(v.y * scale);
    o.z = f2bf(v.z * scale); o.w = f2bf(v.w * scale);
    ((ushort4*)out)[i] = o;
}

// ---------------- prep: V[bh][s][d] fp32 -> Vt[bh][d][s] bf16 ----------------
__global__ __launch_bounds__(256)
void transpose_v(const float* __restrict__ V, unsigned short* __restrict__ Vt)
{
    __shared__ __align__(16) unsigned short vt[64 * 72];  // [d][r], stride 72
    const int bh = blockIdx.x >> 5;
    const int s0 = (blockIdx.x & 31) * 64;
    const int t  = threadIdx.x;

    const float4* src = (const float4*)(V + ((size_t)bh * SL + s0) * DD);
    #pragma unroll
    for (int i = 0; i < 4; ++i) {
        int idx = t + i * 256;
        int r = idx >> 4, d4 = idx & 15;
        float4 v = src[r * 16 + d4];
        vt[(d4 * 4 + 0) * 72 + r] = f2bf(v.x);
        vt[(d4 * 4 + 1) * 72 + r] = f2bf(v.y);
        vt[(d4 * 4 + 2) * 72 + r] = f2bf(v.z);
        vt[(d4 * 4 + 3) * 72 + r] = f2bf(v.w);
    }
    __syncthreads();
    const int d = t >> 2, seg = t & 3;
    unsigned short* dst = Vt + ((size_t)bh * DD + d) * SL + s0 + seg * 16;
    uint4 p0 = *(const uint4*)&vt[d * 72 + seg * 16];
    uint4 p1 = *(const uint4*)&vt[d * 72 + seg * 16 + 8];
    *(uint4*)dst = p0;
    *(uint4*)(dst + 8) = p1;
}

// ---------------- main fused attention ---------------------------------------
__global__ __launch_bounds__(NT, 4)
void attn_mfma(const unsigned short* __restrict__ Qb,
               const unsigned short* __restrict__ Kb,
               const unsigned short* __restrict__ Vt,
               const float* __restrict__ Mg,
               const int* __restrict__ MNg,
               float* __restrict__ Og)
{
    __shared__ __align__(16) float slab[32 * SLABW];   // 32 rows x 256-col P tile
    __shared__ float lsx[4][16];

    const int tid  = threadIdx.x;
    const int w    = tid >> 6;
    const int lane = tid & 63;
    const int l15  = lane & 15;
    const int qd   = lane >> 4;
    const int rowhalf = w >> 1;      // which 16 of the 32 rows (QK/exp & PV rows)
    const int colhalf = w & 1;       // QK: which 128 cols; PV: which 32 d

    // 1024 blocks: xcd = lin&7, 4 bh per XCD, 32 fold-pairs per bh.
    const int lin  = blockIdx.x;
    const int xcd  = lin & 7;
    const int iloc = lin >> 3;       // 0..127
    const int g    = iloc & 31;      // fold pair: groups g and 63-g (32 rows each)
    const int bh   = xcd * 4 + (iloc >> 5);
    const int b    = bh >> 4;

    const int diag = (MNg[0] != 0) ? -1 : 0;

    const unsigned short* Qh  = Qb + (size_t)bh * SL * DD;
    const unsigned short* Kh  = Kb + (size_t)bh * SL * DD;
    const unsigned short* Vth = Vt + (size_t)bh * DD * SL;
    float* Sb = Og + (size_t)NB * NH * SL * DD + (size_t)bh * SL * SL;
    float* Ob = Og + (size_t)bh * SL * DD;

    for (int sweep = 0; sweep < 2; ++sweep) {
        const int R0 = sweep ? (2016 - g * 32) : (g * 32);

        // Degeneracy across ALL 32 rows (block-uniform M).
        int degflag = 0;
        if (lane < 32) {
            int row = R0 + lane;
            float m = Mg[(size_t)b * SL + row];
            degflag = (m == 0.0f) || (row + diag < 0);
        }
        const bool deg32 = __any(degflag);
        const int M = deg32 ? 8 : (((R0 + 31 + diag) >> 8) + 1);   // 256-col megas

        // This wave's 16 rows.
        int rlim[4];
        #pragma unroll
        for (int reg = 0; reg < 4; ++reg) {
            int row = R0 + rowhalf * 16 + qd * 4 + reg;
            float m = Mg[(size_t)b * SL + row];
            int rl = row + diag;
            if (m == 0.0f) rl = -1;
            rlim[reg] = rl;
        }

        // Q A-frags for this sweep's rows (Q pre-scaled by 0.125*log2e).
        const unsigned short* qrow = Qh + (size_t)(R0 + rowhalf * 16 + l15) * DD + qd * 8;
        bf16x8 qf0 = *(const bf16x8*)qrow;
        bf16x8 qf1 = *(const bf16x8*)(qrow + 32);

        auto ldK = [&](int ct, bf16x8& f0, bf16x8& f1) {
            const unsigned short* kr = Kh + (size_t)(ct + l15) * DD + qd * 8;
            f0 = *(const bf16x8*)kr;
            f1 = *(const bf16x8*)(kr + 32);
        };

        // ---------- Phase A: row sums over this wave's col-half --------------
        float lacc[4] = {0.0f, 0.0f, 0.0f, 0.0f};
        {
            auto cmpA = [&](int ct, bf16x8 f0, bf16x8 f1) {
                f32x4 acc = {0.0f, 0.0f, 0.0f, 0.0f};
                __builtin_amdgcn_s_setprio(1);
                acc = __builtin_amdgcn_mfma_f32_16x16x32_bf16(qf0, f0, acc, 0, 0, 0);
                acc = __builtin_amdgcn_mfma_f32_16x16x32_bf16(qf1, f1, acc, 0, 0, 0);
                __builtin_amdgcn_s_setprio(0);
                const int col = ct + l15;
                #pragma unroll
                for (int reg = 0; reg < 4; ++reg)
                    lacc[reg] += (col <= rlim[reg]) ? __builtin_exp2f(acc[reg]) : 0.0f;
            };
            auto tcol = [&](int t) {
                return ((t >> 3) << 8) + colhalf * 128 + ((t & 7) << 4);
            };
            const int T = M * 8;            // even, >= 8
            bf16x8 A0, A1, B0, B1;
            ldK(tcol(0), A0, A1);
            for (int t = 0; t < T; t += 2) {
                ldK(tcol(t + 1), B0, B1);
                cmpA(tcol(t), A0, A1);
                if (t + 2 < T) ldK(tcol(t + 2), A0, A1);
                cmpA(tcol(t + 1), B0, B1);
            }
        }

        // Reduce over l15, combine with col-half partner via LDS.
        float lsum[4];
        #pragma unroll
        for (int reg = 0; reg < 4; ++reg) {
            float s = lacc[reg];
            s += __shfl_xor(s, 1);  s += __shfl_xor(s, 2);
            s += __shfl_xor(s, 4);  s += __shfl_xor(s, 8);
            lsum[reg] = s;
        }
        if (l15 == 0) {
            #pragma unroll
            for (int reg = 0; reg < 4; ++reg)
                lsx[w][qd * 4 + reg] = lsum[reg];
        }
        lds_barrier();
        float pmul[4], pfill[4];
        #pragma unroll
        for (int reg = 0; reg < 4; ++reg) {
            float tot = lsum[reg] + lsx[w ^ 1][qd * 4 + reg];
            pmul[reg]  = (rlim[reg] < 0) ? 0.0f : 1.0f / tot;
            pfill[reg] = (rlim[reg] < 0) ? (1.0f / (float)SL) : 0.0f;
        }

        // ---------- Phase B: per 256-col mega: QK -> slab -> P store + PV ----
        f32x4 oacc[2];
        oacc[0] = (f32x4){0.0f, 0.0f, 0.0f, 0.0f};
        oacc[1] = (f32x4){0.0f, 0.0f, 0.0f, 0.0f};

        for (int mc = 0; mc < M; ++mc) {
            const int C0 = mc << 8;
            // QK + exp into this wave's 16x128 slab quadrant (1-ahead K pipe).
            {
                bf16x8 a0, a1, b0, b1;
                ldK(C0 + colhalf * 128, a0, a1);
                #pragma unroll
                for (int t = 0; t < 8; ++t) {
                    bf16x8 f0 = (t & 1) ? b0 : a0;
                    bf16x8 f1 = (t & 1) ? b1 : a1;
                    if (t < 7) {
                        if (t & 1) ldK(C0 + colhalf * 128 + ((t + 1) << 4), a0, a1);
                        else       ldK(C0 + colhalf * 128 + ((t + 1) << 4), b0, b1);
                    }
                    f32x4 acc = {0.0f, 0.0f, 0.0f, 0.0f};
                    __builtin_amdgcn_s_setprio(1);
                    acc = __builtin_amdgcn_mfma_f32_16x16x32_bf16(qf0, f0, acc, 0, 0, 0);
                    acc = __builtin_amdgcn_mfma_f32_16x16x32_bf16(qf1, f1, acc, 0, 0, 0);
                    __builtin_amdgcn_s_setprio(0);
                    const int scol = colhalf * 128 + (t << 4) + l15;
                    const int col  = C0 + scol;
                    #pragma unroll
                    for (int reg = 0; reg < 4; ++reg) {
                        float val = (col <= rlim[reg]) ? __builtin_exp2f(acc[reg]) * pmul[reg]
                                                       : pfill[reg];
                        slab[(rowhalf * 16 + qd * 4 + reg) * SLABW + scol] = val;
                    }
                }
            }
            lds_barrier();
            // P store: 8 rows x 1KB fully-contiguous runs per instruction.
            #pragma unroll
            for (int i = 0; i < 8; ++i) {
                int rr = w * 8 + i;
                *(float4*)(Sb + (size_t)(R0 + rr) * SL + C0 + lane * 4) =
                    *(const float4*)&slab[rr * SLABW + lane * 4];
            }
            // PV over full 256 cols for this wave's 16 rows, d-half = colhalf*32.
            #pragma unroll
            for (int ks = 0; ks < 8; ++ks) {
                const float* pr = &slab[(rowhalf * 16 + l15) * SLABW + ks * 32 + qd * 8];
                float4 x = *(const float4*)pr;
                float4 y = *(const float4*)(pr + 4);
                bf16x8 f;
                f[0] = (short)f2bf(x.x); f[1] = (short)f2bf(x.y);
                f[2] = (short)f2bf(x.z); f[3] = (short)f2bf(x.w);
                f[4] = (short)f2bf(y.x); f[5] = (short)f2bf(y.y);
                f[6] = (short)f2bf(y.z); f[7] = (short)f2bf(y.w);
                #pragma unroll
                for (int nt = 0; nt < 2; ++nt) {
                    const unsigned short* vr = Vth
                        + (size_t)(colhalf * 32 + nt * 16 + l15) * SL + C0 + ks * 32 + qd * 8;
                    bf16x8 v = *(const bf16x8*)vr;
                    __builtin_amdgcn_s_setprio(1);
                    oacc[nt] = __builtin_amdgcn_mfma_f32_16x16x32_bf16(f, v, oacc[nt], 0, 0, 0);
                    __builtin_amdgcn_s_setprio(0);
                }
            }
            lds_barrier();
        }

        // Zero region: rows w*8..w*8+7, cols [M*256, 2048), dense runs.
        {
            const int zc0 = M << 8;
            float4 z = make_float4(0.0f, 0.0f, 0.0f, 0.0f);
            for (int i = 0; i < 8; ++i) {
                float* rowp = Sb + (size_t)(R0 + w * 8 + i) * SL;
                for (int c = zc0 + (lane << 2); c < SL; c += 256)
                    *(float4*)(rowp + c) = z;
            }
        }

        // O epilogue: stage 32x64 in slab, coalesced store.
        #pragma unroll
        for (int nt = 0; nt < 2; ++nt)
            #pragma unroll
            for (int reg = 0; reg < 4; ++reg)
                slab[(rowhalf * 16 + qd * 4 + reg) * SLABW + colhalf * 32 + nt * 16 + l15] =
                    oacc[nt][reg];
        lds_barrier();
        #pragma unroll
        for (int ii = 0; ii < 2; ++ii) {
            int rr = w * 8 + ii * 4 + (lane >> 4);
            int c4 = lane & 15;
            *(float4*)(Ob + (size_t)(R0 + rr) * DD + c4 * 4) =
                *(const float4*)&slab[rr * SLABW + c4 * 4];
        }
        lds_barrier();   // slab free for next sweep
    }
}

extern "C" void kernel_launch(void* const* d_in, const int* in_sizes, int n_in,
                              void* d_out, int out_size, void* d_ws, size_t ws_size,
                              hipStream_t stream)
{
    const float* q  = (const float*)d_in[0];
    const float* k  = (const float*)d_in[1];
    const float* v  = (const float*)d_in[2];
    const float* mk = (const float*)d_in[3];
    const int*   mn = (const int*)d_in[4];
    float* out = (float*)d_out;

    const size_t nElem = (size_t)NB * NH * SL * DD;   // 4,194,304
    unsigned short* Qb = (unsigned short*)d_ws;
    unsigned short* Kp = Qb + nElem;
    unsigned short* Vp = Kp + nElem;

    const int n4 = (int)(nElem / 4);
    // Q pre-scaled by (1/8)*log2(e): QK^T lands directly in exp2 domain.
    cvt_bf16<<<n4 / 256, 256, 0, stream>>>(q, Qb, n4, 0.125f * 1.44269504f);
    cvt_bf16<<<n4 / 256, 256, 0, stream>>>(k, Kp, n4, 1.0f);
    transpose_v<<<NB * NH * (SL / 64), 256, 0, stream>>>(v, Vp);

    // 1024 blocks: 8 XCD x 4 bh x 32 fold-pairs. Uniform work per block.
    attn_mfma<<<1024, NT, 0, stream>>>(Qb, Kp, Vp, mk, mn, out);
}

// Round 9
// 648.816 us; speedup vs baseline: 1.2360x; 1.1337x over previous
//
#include <hip/hip_runtime.h>
#include <math.h>

// B=2,H=16,S=2048,D=64 fp32 attention, outputs (O, P). MFMA bf16.
// 1024 blocks; block = fold-pair of 32-row groups (g, 63-g), two sweeps.
// This round: cooperative async K/V staging into XOR-swizzled LDS via
// global_load_lds (pre-swizzled global source, linear LDS dest), counted
// vmcnt so P stores + K prefetch stay in flight. Theory: per-wave L2
// gather latency on the dependent path was the wall (all pipes idle).
#define NB 2
#define NH 16
#define SL 2048
#define DD 64
#define KC 64
#define NCH (SL / KC)
#define NT 256
#define SLW 68           // slab fp32 row stride (64 + 4)

typedef short bf16x8 __attribute__((ext_vector_type(8)));
typedef float f32x4  __attribute__((ext_vector_type(4)));

__device__ __forceinline__ unsigned short f2bf(float x) {
    unsigned u = __float_as_uint(x);
    u += 0x7fffu + ((u >> 16) & 1u);     // round-to-nearest-even
    return (unsigned short)(u >> 16);
}

// LDS-only barrier: waits local ops, leaves global loads/stores in flight.
__device__ __forceinline__ void lds_barrier() {
    asm volatile("s_waitcnt lgkmcnt(0)\n\ts_barrier" ::: "memory");
}

// Async 16B/lane global->LDS. dst must be wave-uniform; HW writes dst+lane*16.
__device__ __forceinline__ void gl_lds16(const void* src, void* dst) {
    __builtin_amdgcn_global_load_lds(
        (const __attribute__((address_space(1))) void*)src,
        (__attribute__((address_space(3))) void*)dst, 16, 0, 0);
}

// ---------------- prep: fp32 -> bf16 elementwise (Q scaled, K raw) -----------
__global__ __launch_bounds__(256)
void cvt_bf16(const float* __restrict__ in, unsigned short* __restrict__ out,
              int n4, float scale)
{
    int i = blockIdx.x * 256 + threadIdx.x;
    if (i >= n4) return;
    float4 v = ((const float4*)in)[i];
    ushort4 o;
    o.x = f2bf(v.x * scale); o.y = f2bf(v.y * scale);
    o.z = f2bf(v.z * scale); o.w = f2bf(v.w * scale);
    ((ushort4*)out)[i] = o;
}

// ---------------- prep: V[bh][s][d] fp32 -> Vt[bh][d][s] bf16 ----------------
__global__ __launch_bounds__(256)
void transpose_v(const float* __restrict__ V, unsigned short* __restrict__ Vt)
{
    __shared__ __align__(16) unsigned short vt[64 * 72];  // [d][r], stride 72
    const int bh = blockIdx.x >> 5;
    const int s0 = (blockIdx.x & 31) * 64;
    const int t  = threadIdx.x;

    const float4* src = (const float4*)(V + ((size_t)bh * SL + s0) * DD);
    #pragma unroll
    for (int i = 0; i < 4; ++i) {
        int idx = t + i * 256;
        int r = idx >> 4, d4 = idx & 15;
        float4 v = src[r * 16 + d4];
        vt[(d4 * 4 + 0) * 72 + r] = f2bf(v.x);
        vt[(d4 * 4 + 1) * 72 + r] = f2bf(v.y);
        vt[(d4 * 4 + 2) * 72 + r] = f2bf(v.z);
        vt[(d4 * 4 + 3) * 72 + r] = f2bf(v.w);
    }
    __syncthreads();
    const int d = t >> 2, seg = t & 3;
    unsigned short* dst = Vt + ((size_t)bh * DD + d) * SL + s0 + seg * 16;
    uint4 p0 = *(const uint4*)&vt[d * 72 + seg * 16];
    uint4 p1 = *(const uint4*)&vt[d * 72 + seg * 16 + 8];
    *(uint4*)dst = p0;
    *(uint4*)(dst + 8) = p1;
}

// ---------------- main fused attention ---------------------------------------
__global__ __launch_bounds__(NT, 4)
void attn_mfma(const unsigned short* __restrict__ Qb,
               const unsigned short* __restrict__ Kb,
               const unsigned short* __restrict__ Vt,
               const float* __restrict__ Mg,
               const int* __restrict__ MNg,
               float* __restrict__ Og)
{
    // K double-buffered (8KB x2), V single (8KB), P slab 32x68 fp32 (8.5KB).
    __shared__ __align__(16) unsigned short kst[2][KC * DD];
    __shared__ __align__(16) unsigned short vst[DD * KC];
    __shared__ __align__(16) float slab[32 * SLW];
    __shared__ float lsx[4][16];

    const int tid  = threadIdx.x;
    const int w    = tid >> 6;
    const int lane = tid & 63;
    const int l15  = lane & 15;
    const int qd   = lane >> 4;
    const int rowhalf = w >> 1;      // which 16 of the 32 q-rows
    const int colhalf = w & 1;       // which 32 cols (QK) / 32 d (PV)

    // 1024 blocks: xcd = lin&7, 4 bh per XCD, 32 fold-pairs per bh.
    const int lin  = blockIdx.x;
    const int xcd  = lin & 7;
    const int iloc = lin >> 3;
    const int g    = iloc & 31;      // fold pair: 32-row groups g and 63-g
    const int bh   = xcd * 4 + (iloc >> 5);
    const int b    = bh >> 4;
    const int diag = (MNg[0] != 0) ? -1 : 0;

    const unsigned short* Qh  = Qb + (size_t)bh * SL * DD;
    const unsigned short* Kh  = Kb + (size_t)bh * SL * DD;
    const unsigned short* Vth = Vt + (size_t)bh * DD * SL;
    float* Sb = Og + (size_t)NB * NH * SL * DD + (size_t)bh * SL * SL;
    float* Ob = Og + (size_t)bh * SL * DD;

    // Staging geometry: 64x128B tile = 8 x 1KB instrs, 2 per wave.
    // LDS[x] holds G[x ^ ((row&7)<<4)]  (pre-swizzled source, linear dest).
    const int srw = lane >> 3;                 // row-in-8 for this lane
    const int sc16 = (lane & 7) ^ srw;         // swizzled col16 to FETCH

    auto stageK = [&](int kc, int dbuf) {
        const unsigned short* base = Kh + (size_t)kc * KC * DD;
        #pragma unroll
        for (int j = 0; j < 2; ++j) {
            int i = w * 2 + j;
            const unsigned short* src = base + (size_t)(i * 8 + srw) * DD + sc16 * 8;
            gl_lds16(src, &kst[dbuf][i * 512]);
        }
    };
    auto stageV = [&](int c0) {
        #pragma unroll
        for (int j = 0; j < 2; ++j) {
            int i = w * 2 + j;
            const unsigned short* src = Vth + (size_t)(i * 8 + srw) * SL + c0 + sc16 * 8;
            gl_lds16(src, &vst[i * 512]);
        }
    };
    // Swizzled 16B read of logical (row r, col16 c16) from a 64x128B LDS tile.
    auto rd16 = [&](const unsigned short* lb, int r, int c16) -> bf16x8 {
        int a = (r * 128 + c16 * 16) ^ ((r & 7) << 4);
        return *(const bf16x8*)((const char*)lb + a);
    };

    for (int sweep = 0; sweep < 2; ++sweep) {
        const int R0 = sweep ? (2016 - g * 32) : (g * 32);

        // Degeneracy across the 32 rows (block-uniform).
        int degflag = 0;
        if (lane < 32) {
            int row = R0 + lane;
            float m = Mg[(size_t)b * SL + row];
            degflag = (m == 0.0f) || (row + diag < 0);
        }
        const bool deg32 = __any(degflag);
        const int N = deg32 ? NCH : (((R0 + 31 + diag) >> 6) + 1);

        // This wave's 16 rows.
        int rlim[4];
        #pragma unroll
        for (int reg = 0; reg < 4; ++reg) {
            int row = R0 + rowhalf * 16 + qd * 4 + reg;
            float m = Mg[(size_t)b * SL + row];
            int rl = row + diag;
            if (m == 0.0f) rl = -1;
            rlim[reg] = rl;
        }

        // Q A-frags (Q pre-scaled by 0.125*log2e -> P = exp2(acc)).
        const unsigned short* qrow = Qh + (size_t)(R0 + rowhalf * 16 + l15) * DD + qd * 8;
        bf16x8 qf0 = *(const bf16x8*)qrow;
        bf16x8 qf1 = *(const bf16x8*)(qrow + 32);

        // ---------------- Phase A: row sums, staged K, dbuf ------------------
        float lacc[4] = {0.0f, 0.0f, 0.0f, 0.0f};
        stageK(0, 0);
        asm volatile("s_waitcnt vmcnt(0)" ::: "memory");
        lds_barrier();
        for (int kc = 0; kc < N; ++kc) {
            const int d = kc & 1;
            if (kc + 1 < N) stageK(kc + 1, d ^ 1);
            const int c0 = kc * KC;
            #pragma unroll
            for (int t = 0; t < 2; ++t) {
                const int ntg = colhalf * 2 + t;
                bf16x8 b0 = rd16(kst[d], ntg * 16 + l15, qd);
                bf16x8 b1 = rd16(kst[d], ntg * 16 + l15, 4 + qd);
                f32x4 acc = {0.0f, 0.0f, 0.0f, 0.0f};
                __builtin_amdgcn_s_setprio(1);
                acc = __builtin_amdgcn_mfma_f32_16x16x32_bf16(qf0, b0, acc, 0, 0, 0);
                acc = __builtin_amdgcn_mfma_f32_16x16x32_bf16(qf1, b1, acc, 0, 0, 0);
                __builtin_amdgcn_s_setprio(0);
                const int col = c0 + ntg * 16 + l15;
                #pragma unroll
                for (int reg = 0; reg < 4; ++reg)
                    lacc[reg] += (col <= rlim[reg]) ? __builtin_exp2f(acc[reg]) : 0.0f;
            }
            asm volatile("s_waitcnt vmcnt(0)" ::: "memory");
            lds_barrier();
        }

        // Reduce over l15; combine with col-half partner via LDS.
        float lsum[4];
        #pragma unroll
        for (int reg = 0; reg < 4; ++reg) {
            float s = lacc[reg];
            s += __shfl_xor(s, 1);  s += __shfl_xor(s, 2);
            s += __shfl_xor(s, 4);  s += __shfl_xor(s, 8);
            lsum[reg] = s;
        }
        if (l15 == 0) {
            #pragma unroll
            for (int reg = 0; reg < 4; ++reg)
                lsx[w][qd * 4 + reg] = lsum[reg];
        }
        lds_barrier();
        float pmul[4], pfill[4];
        #pragma unroll
        for (int reg = 0; reg < 4; ++reg) {
            float tot = lsum[reg] + lsx[w ^ 1][qd * 4 + reg];
            pmul[reg]  = (rlim[reg] < 0) ? 0.0f : 1.0f / tot;
            pfill[reg] = (rlim[reg] < 0) ? (1.0f / (float)SL) : 0.0f;
        }

        // ---------------- Phase B: staged K dbuf + staged V ------------------
        f32x4 oacc[2];
        oacc[0] = (f32x4){0.0f, 0.0f, 0.0f, 0.0f};
        oacc[1] = (f32x4){0.0f, 0.0f, 0.0f, 0.0f};

        stageK(0, 0);
        asm volatile("s_waitcnt vmcnt(0)" ::: "memory");
        lds_barrier();
        for (int kc = 0; kc < N; ++kc) {
            const int d  = kc & 1;
            const int c0 = kc * KC;
            stageV(c0);                          // 2 loads (oldest this chunk)
            const bool pk = (kc + 1 < N);
            if (pk) stageK(kc + 1, d ^ 1);       // 2 loads (stay in flight)
            // QK + exp -> slab quadrant.
            #pragma unroll
            for (int t = 0; t < 2; ++t) {
                const int ntg = colhalf * 2 + t;
                bf16x8 b0 = rd16(kst[d], ntg * 16 + l15, qd);
                bf16x8 b1 = rd16(kst[d], ntg * 16 + l15, 4 + qd);
                f32x4 acc = {0.0f, 0.0f, 0.0f, 0.0f};
                __builtin_amdgcn_s_setprio(1);
                acc = __builtin_amdgcn_mfma_f32_16x16x32_bf16(qf0, b0, acc, 0, 0, 0);
                acc = __builtin_amdgcn_mfma_f32_16x16x32_bf16(qf1, b1, acc, 0, 0, 0);
                __builtin_amdgcn_s_setprio(0);
                const int col = c0 + ntg * 16 + l15;
                #pragma unroll
                for (int reg = 0; reg < 4; ++reg) {
                    float val = (col <= rlim[reg]) ? __builtin_exp2f(acc[reg]) * pmul[reg]
                                                   : pfill[reg];
                    slab[(rowhalf * 16 + qd * 4 + reg) * SLW + ntg * 16 + l15] = val;
                }
            }
            // Drain my V (allow K prefetch to stay in flight), then sync.
            if (pk) { asm volatile("s_waitcnt vmcnt(2)" ::: "memory"); }
            else    { asm volatile("s_waitcnt vmcnt(0)" ::: "memory"); }
            lds_barrier();                       // slab + all waves' V ready
            // P store: 2 instrs x 4 rows x 256B.
            #pragma unroll
            for (int ii = 0; ii < 2; ++ii) {
                int rr = w * 8 + ii * 4 + (lane >> 4);
                int c4 = lane & 15;
                *(float4*)(Sb + (size_t)(R0 + rr) * SL + c0 + c4 * 4) =
                    *(const float4*)&slab[rr * SLW + c4 * 4];
            }
            // PV from slab (full 64 cols) x staged V (own d-half).
            #pragma unroll
            for (int ks = 0; ks < 2; ++ks) {
                const float* pr = &slab[(rowhalf * 16 + l15) * SLW + ks * 32 + qd * 8];
                float4 x = *(const float4*)pr;
                float4 y = *(const float4*)(pr + 4);
                bf16x8 f;
                f[0] = (short)f2bf(x.x); f[1] = (short)f2bf(x.y);
                f[2] = (short)f2bf(x.z); f[3] = (short)f2bf(x.w);
                f[4] = (short)f2bf(y.x); f[5] = (short)f2bf(y.y);
                f[6] = (short)f2bf(y.z); f[7] = (short)f2bf(y.w);
                #pragma unroll
                for (int nt = 0; nt < 2; ++nt) {
                    bf16x8 v = rd16(vst, colhalf * 32 + nt * 16 + l15, ks * 4 + qd);
                    __builtin_amdgcn_s_setprio(1);
                    oacc[nt] = __builtin_amdgcn_mfma_f32_16x16x32_bf16(f, v, oacc[nt], 0, 0, 0);
                    __builtin_amdgcn_s_setprio(0);
                }
            }
            if (pk) {
                asm volatile("s_waitcnt vmcnt(2)" ::: "memory");  // my K staged
                lds_barrier();                    // all K staged + slab reusable
            }
        }
        lds_barrier();                            // slab free for epilogue

        // Zero region: rows w*8..+7, cols [N*64, 2048), dense runs.
        {
            const int zc0 = N * KC;
            float4 z = make_float4(0.0f, 0.0f, 0.0f, 0.0f);
            for (int i = 0; i < 8; ++i) {
                float* rowp = Sb + (size_t)(R0 + w * 8 + i) * SL;
                for (int c = zc0 + (lane << 2); c < SL; c += 256)
                    *(float4*)(rowp + c) = z;
            }
        }

        // O epilogue: stage 32x64 in slab, coalesced store.
        #pragma unroll
        for (int nt = 0; nt < 2; ++nt)
            #pragma unroll
            for (int reg = 0; reg < 4; ++reg)
                slab[(rowhalf * 16 + qd * 4 + reg) * SLW + colhalf * 32 + nt * 16 + l15] =
                    oacc[nt][reg];
        lds_barrier();
        #pragma unroll
        for (int ii = 0; ii < 2; ++ii) {
            int rr = w * 8 + ii * 4 + (lane >> 4);
            int c4 = lane & 15;
            *(float4*)(Ob + (size_t)(R0 + rr) * DD + c4 * 4) =
                *(const float4*)&slab[rr * SLW + c4 * 4];
        }
        lds_barrier();   // LDS free for next sweep
    }
}

extern "C" void kernel_launch(void* const* d_in, const int* in_sizes, int n_in,
                              void* d_out, int out_size, void* d_ws, size_t ws_size,
                              hipStream_t stream)
{
    const float* q  = (const float*)d_in[0];
    const float* k  = (const float*)d_in[1];
    const float* v  = (const float*)d_in[2];
    const float* mk = (const float*)d_in[3];
    const int*   mn = (const int*)d_in[4];
    float* out = (float*)d_out;

    const size_t nElem = (size_t)NB * NH * SL * DD;   // 4,194,304
    unsigned short* Qb = (unsigned short*)d_ws;
    unsigned short* Kp = Qb + nElem;
    unsigned short* Vp = Kp + nElem;

    const int n4 = (int)(nElem / 4);
    // Q pre-scaled by (1/8)*log2(e): QK^T lands directly in exp2 domain.
    cvt_bf16<<<n4 / 256, 256, 0, stream>>>(q, Qb, n4, 0.125f * 1.44269504f);
    cvt_bf16<<<n4 / 256, 256, 0, stream>>>(k, Kp, n4, 1.0f);
    transpose_v<<<NB * NH * (SL / 64), 256, 0, stream>>>(v, Vp);

    // 1024 blocks: 8 XCD x 4 bh x 32 fold-pairs. Uniform work per block.
    attn_mfma<<<1024, NT, 0, stream>>>(Qb, Kp, Vp, mk, mn, out);
}

// Round 10
// 648.181 us; speedup vs baseline: 1.2372x; 1.0010x over previous
//
#include <hip/hip_runtime.h>
#include <math.h>

// B=2,H=16,S=2048,D=64 fp32 attention, outputs (O, P). MFMA bf16.
// 1024 blocks; block = fold-pair of 32-row groups (g, 63-g), two sweeps.
// R10: counted-vmcnt schedule fix. R9 drained 6/8 fresh P stores per chunk
// (vmcnt(2) after stores in queue order); now end-of-chunk waits vmcnt(8)
// so stores stay in flight. Phase A: 3-buffer K rotation (reuses V buffer),
// counted vmcnt(2) with one chunk of slack instead of post-compute drain.
#define NB 2
#define NH 16
#define SL 2048
#define DD 64
#define KC 64
#define NCH (SL / KC)
#define NT 256
#define SLW 68           // slab fp32 row stride (64 + 4)

typedef short bf16x8 __attribute__((ext_vector_type(8)));
typedef float f32x4  __attribute__((ext_vector_type(4)));

__device__ __forceinline__ unsigned short f2bf(float x) {
    unsigned u = __float_as_uint(x);
    u += 0x7fffu + ((u >> 16) & 1u);     // round-to-nearest-even
    return (unsigned short)(u >> 16);
}

// LDS-only barrier: waits local ops, leaves global loads/stores in flight.
__device__ __forceinline__ void lds_barrier() {
    asm volatile("s_waitcnt lgkmcnt(0)\n\ts_barrier" ::: "memory");
}
#define WAITV(n) asm volatile("s_waitcnt vmcnt(" #n ")" ::: "memory")

// Async 16B/lane global->LDS. dst wave-uniform; HW writes dst+lane*16.
__device__ __forceinline__ void gl_lds16(const void* src, void* dst) {
    __builtin_amdgcn_global_load_lds(
        (const __attribute__((address_space(1))) void*)src,
        (__attribute__((address_space(3))) void*)dst, 16, 0, 0);
}

// ---------------- prep: fp32 -> bf16 elementwise (Q scaled, K raw) -----------
__global__ __launch_bounds__(256)
void cvt_bf16(const float* __restrict__ in, unsigned short* __restrict__ out,
              int n4, float scale)
{
    int i = blockIdx.x * 256 + threadIdx.x;
    if (i >= n4) return;
    float4 v = ((const float4*)in)[i];
    ushort4 o;
    o.x = f2bf(v.x * scale); o.y = f2bf(v.y * scale);
    o.z = f2bf(v.z * scale); o.w = f2bf(v.w * scale);
    ((ushort4*)out)[i] = o;
}

// ---------------- prep: V[bh][s][d] fp32 -> Vt[bh][d][s] bf16 ----------------
__global__ __launch_bounds__(256)
void transpose_v(const float* __restrict__ V, unsigned short* __restrict__ Vt)
{
    __shared__ __align__(16) unsigned short vt[64 * 72];  // [d][r], stride 72
    const int bh = blockIdx.x >> 5;
    const int s0 = (blockIdx.x & 31) * 64;
    const int t  = threadIdx.x;

    const float4* src = (const float4*)(V + ((size_t)bh * SL + s0) * DD);
    #pragma unroll
    for (int i = 0; i < 4; ++i) {
        int idx = t + i * 256;
        int r = idx >> 4, d4 = idx & 15;
        float4 v = src[r * 16 + d4];
        vt[(d4 * 4 + 0) * 72 + r] = f2bf(v.x);
        vt[(d4 * 4 + 1) * 72 + r] = f2bf(v.y);
        vt[(d4 * 4 + 2) * 72 + r] = f2bf(v.z);
        vt[(d4 * 4 + 3) * 72 + r] = f2bf(v.w);
    }
    __syncthreads();
    const int d = t >> 2, seg = t & 3;
    unsigned short* dst = Vt + ((size_t)bh * DD + d) * SL + s0 + seg * 16;
    uint4 p0 = *(const uint4*)&vt[d * 72 + seg * 16];
    uint4 p1 = *(const uint4*)&vt[d * 72 + seg * 16 + 8];
    *(uint4*)dst = p0;
    *(uint4*)(dst + 8) = p1;
}

// ---------------- main fused attention ---------------------------------------
__global__ __launch_bounds__(NT, 4)
void attn_mfma(const unsigned short* __restrict__ Qb,
               const unsigned short* __restrict__ Kb,
               const unsigned short* __restrict__ Vt,
               const float* __restrict__ Mg,
               const int* __restrict__ MNg,
               float* __restrict__ Og)
{
    // kb: Phase A = 3-deep K rotation; Phase B = K dbuf (0,1) + V (2).
    __shared__ __align__(16) unsigned short kb[3][KC * DD];   // 3 x 8KB
    __shared__ __align__(16) float slab[32 * SLW];            // 8.7KB
    __shared__ float lsx[4][16];

    const int tid  = threadIdx.x;
    const int w    = tid >> 6;
    const int lane = tid & 63;
    const int l15  = lane & 15;
    const int qd   = lane >> 4;
    const int rowhalf = w >> 1;      // which 16 of the 32 q-rows
    const int colhalf = w & 1;       // which 32 cols (QK) / 32 d (PV)

    // 1024 blocks: xcd = lin&7, 4 bh per XCD, 32 fold-pairs per bh.
    const int lin  = blockIdx.x;
    const int xcd  = lin & 7;
    const int iloc = lin >> 3;
    const int g    = iloc & 31;      // fold pair: 32-row groups g and 63-g
    const int bh   = xcd * 4 + (iloc >> 5);
    const int b    = bh >> 4;
    const int diag = (MNg[0] != 0) ? -1 : 0;

    const unsigned short* Qh  = Qb + (size_t)bh * SL * DD;
    const unsigned short* Kh  = Kb + (size_t)bh * SL * DD;
    const unsigned short* Vth = Vt + (size_t)bh * DD * SL;
    float* Sb = Og + (size_t)NB * NH * SL * DD + (size_t)bh * SL * SL;
    float* Ob = Og + (size_t)bh * SL * DD;

    // Staging geometry: 64x128B tile = 8 x 1KB instrs, 2 per wave.
    // LDS[x] holds G[x ^ ((row&7)<<4)] (pre-swizzled source, linear dest).
    const int srw = lane >> 3;
    const int sc16 = (lane & 7) ^ srw;

    auto stageK = [&](int kc, int dbuf) {
        const unsigned short* base = Kh + (size_t)kc * KC * DD;
        #pragma unroll
        for (int j = 0; j < 2; ++j) {
            int i = w * 2 + j;
            const unsigned short* src = base + (size_t)(i * 8 + srw) * DD + sc16 * 8;
            gl_lds16(src, &kb[dbuf][i * 512]);
        }
    };
    auto stageV = [&](int c0) {
        #pragma unroll
        for (int j = 0; j < 2; ++j) {
            int i = w * 2 + j;
            const unsigned short* src = Vth + (size_t)(i * 8 + srw) * SL + c0 + sc16 * 8;
            gl_lds16(src, &kb[2][i * 512]);
        }
    };
    auto rd16 = [&](const unsigned short* lb, int r, int c16) -> bf16x8 {
        int a = (r * 128 + c16 * 16) ^ ((r & 7) << 4);
        return *(const bf16x8*)((const char*)lb + a);
    };

    for (int sweep = 0; sweep < 2; ++sweep) {
        const int R0 = sweep ? (2016 - g * 32) : (g * 32);

        // Degeneracy across the 32 rows (block-uniform).
        int degflag = 0;
        if (lane < 32) {
            int row = R0 + lane;
            float m = Mg[(size_t)b * SL + row];
            degflag = (m == 0.0f) || (row + diag < 0);
        }
        const bool deg32 = __any(degflag);
        const int N = deg32 ? NCH : (((R0 + 31 + diag) >> 6) + 1);

        // This wave's 16 rows.
        int rlim[4];
        #pragma unroll
        for (int reg = 0; reg < 4; ++reg) {
            int row = R0 + rowhalf * 16 + qd * 4 + reg;
            float m = Mg[(size_t)b * SL + row];
            int rl = row + diag;
            if (m == 0.0f) rl = -1;
            rlim[reg] = rl;
        }

        // Q A-frags (Q pre-scaled by 0.125*log2e -> P = exp2(acc)).
        const unsigned short* qrow = Qh + (size_t)(R0 + rowhalf * 16 + l15) * DD + qd * 8;
        bf16x8 qf0 = *(const bf16x8*)qrow;
        bf16x8 qf1 = *(const bf16x8*)(qrow + 32);

        // -------- Phase A: row sums; 3-buffer K rotation, 1-ahead, 1 barrier -
        // Per iter: stage(kc+1 -> (kc+1)%3) [buffer last read at kc-2, guarded
        // by iter kc-1's barrier]; counted wait for K(kc) (issued at iter kc-1,
        // a full chunk of slack); barrier publishes; compute.
        float lacc[4] = {0.0f, 0.0f, 0.0f, 0.0f};
        stageK(0, 0);
        for (int kc = 0; kc < N; ++kc) {
            const int d = kc % 3;
            if (kc + 1 < N) { stageK(kc + 1, (kc + 1) % 3); WAITV(2); }
            else            { WAITV(0); }
            lds_barrier();
            const int c0 = kc * KC;
            #pragma unroll
            for (int t = 0; t < 2; ++t) {
                const int ntg = colhalf * 2 + t;
                bf16x8 b0 = rd16(kb[d], ntg * 16 + l15, qd);
                bf16x8 b1 = rd16(kb[d], ntg * 16 + l15, 4 + qd);
                f32x4 acc = {0.0f, 0.0f, 0.0f, 0.0f};
                __builtin_amdgcn_s_setprio(1);
                acc = __builtin_amdgcn_mfma_f32_16x16x32_bf16(qf0, b0, acc, 0, 0, 0);
                acc = __builtin_amdgcn_mfma_f32_16x16x32_bf16(qf1, b1, acc, 0, 0, 0);
                __builtin_amdgcn_s_setprio(0);
                const int col = c0 + ntg * 16 + l15;
                #pragma unroll
                for (int reg = 0; reg < 4; ++reg)
                    lacc[reg] += (col <= rlim[reg]) ? __builtin_exp2f(acc[reg]) : 0.0f;
            }
        }

        // Reduce over l15; combine with col-half partner via LDS.
        float lsum[4];
        #pragma unroll
        for (int reg = 0; reg < 4; ++reg) {
            float s = lacc[reg];
            s += __shfl_xor(s, 1);  s += __shfl_xor(s, 2);
            s += __shfl_xor(s, 4);  s += __shfl_xor(s, 8);
            lsum[reg] = s;
        }
        lds_barrier();               // all waves done reading kb[] (Phase A)
        if (l15 == 0) {
            #pragma unroll
            for (int reg = 0; reg < 4; ++reg)
                lsx[w][qd * 4 + reg] = lsum[reg];
        }
        lds_barrier();
        float pmul[4], pfill[4];
        #pragma unroll
        for (int reg = 0; reg < 4; ++reg) {
            float tot = lsum[reg] + lsx[w ^ 1][qd * 4 + reg];
            pmul[reg]  = (rlim[reg] < 0) ? 0.0f : 1.0f / tot;
            pfill[reg] = (rlim[reg] < 0) ? (1.0f / (float)SL) : 0.0f;
        }

        // -------- Phase B: K dbuf + V; stores NEVER drained mid-loop ---------
        f32x4 oacc[2];
        oacc[0] = (f32x4){0.0f, 0.0f, 0.0f, 0.0f};
        oacc[1] = (f32x4){0.0f, 0.0f, 0.0f, 0.0f};

        stageK(0, 0);
        WAITV(0);
        lds_barrier();
        for (int kc = 0; kc < N; ++kc) {
            const int d  = kc & 1;
            const int c0 = kc * KC;
            const bool pk = (kc + 1 < N);
            stageV(c0);                          // V(kc): oldest this chunk
            if (pk) stageK(kc + 1, d ^ 1);       // K(kc+1): stays in flight
            // QK + exp -> slab quadrant (kst[d] resident from prev chunk).
            #pragma unroll
            for (int t = 0; t < 2; ++t) {
                const int ntg = colhalf * 2 + t;
                bf16x8 b0 = rd16(kb[d], ntg * 16 + l15, qd);
                bf16x8 b1 = rd16(kb[d], ntg * 16 + l15, 4 + qd);
                f32x4 acc = {0.0f, 0.0f, 0.0f, 0.0f};
                __builtin_amdgcn_s_setprio(1);
                acc = __builtin_amdgcn_mfma_f32_16x16x32_bf16(qf0, b0, acc, 0, 0, 0);
                acc = __builtin_amdgcn_mfma_f32_16x16x32_bf16(qf1, b1, acc, 0, 0, 0);
                __builtin_amdgcn_s_setprio(0);
                const int col = c0 + ntg * 16 + l15;
                #pragma unroll
                for (int reg = 0; reg < 4; ++reg) {
                    float val = (col <= rlim[reg]) ? __builtin_exp2f(acc[reg]) * pmul[reg]
                                                   : pfill[reg];
                    slab[(rowhalf * 16 + qd * 4 + reg) * SLW + ntg * 16 + l15] = val;
                }
            }
            // Wait V(kc) only: newest 2 allowed = K(kc+1). Old stores (kc-1)
            // are a full chunk stale -> free. Fresh stores not yet issued.
            if (pk) { WAITV(2); } else { WAITV(0); }
            lds_barrier();                       // slab + V published
            // P store: 2 instrs x 4 rows x 256B; stay in flight.
            #pragma unroll
            for (int ii = 0; ii < 2; ++ii) {
                int rr = w * 8 + ii * 4 + (lane >> 4);
                int c4 = lane & 15;
                *(float4*)(Sb + (size_t)(R0 + rr) * SL + c0 + c4 * 4) =
                    *(const float4*)&slab[rr * SLW + c4 * 4];
            }
            // PV from slab (full 64 cols) x staged V (own d-half).
            #pragma unroll
            for (int ks = 0; ks < 2; ++ks) {
                const float* pr = &slab[(rowhalf * 16 + l15) * SLW + ks * 32 + qd * 8];
                float4 x = *(const float4*)pr;
                float4 y = *(const float4*)(pr + 4);
                bf16x8 f;
                f[0] = (short)f2bf(x.x); f[1] = (short)f2bf(x.y);
                f[2] = (short)f2bf(x.z); f[3] = (short)f2bf(x.w);
                f[4] = (short)f2bf(y.x); f[5] = (short)f2bf(y.y);
                f[6] = (short)f2bf(y.z); f[7] = (short)f2bf(y.w);
                #pragma unroll
                for (int nt = 0; nt < 2; ++nt) {
                    bf16x8 v = rd16(kb[2], colhalf * 32 + nt * 16 + l15, ks * 4 + qd);
                    __builtin_amdgcn_s_setprio(1);
                    oacc[nt] = __builtin_amdgcn_mfma_f32_16x16x32_bf16(f, v, oacc[nt], 0, 0, 0);
                    __builtin_amdgcn_s_setprio(0);
                }
            }
            // Wait K(kc+1) only: allow the 8 fresh P stores to stay in flight.
            // Queue (old->new): K(kc+1) x2, stores(kc) x8  ->  vmcnt(8).
            if (pk) { WAITV(8); }
            lds_barrier();                       // K published; slab/V reusable
        }

        // Zero region: rows w*8..+7, cols [N*64, 2048), dense runs.
        {
            const int zc0 = N * KC;
            float4 z = make_float4(0.0f, 0.0f, 0.0f, 0.0f);
            for (int i = 0; i < 8; ++i) {
                float* rowp = Sb + (size_t)(R0 + w * 8 + i) * SL;
                for (int c = zc0 + (lane << 2); c < SL; c += 256)
                    *(float4*)(rowp + c) = z;
            }
        }

        // O epilogue: stage 32x64 in slab, coalesced store.
        #pragma unroll
        for (int nt = 0; nt < 2; ++nt)
            #pragma unroll
            for (int reg = 0; reg < 4; ++reg)
                slab[(rowhalf * 16 + qd * 4 + reg) * SLW + colhalf * 32 + nt * 16 + l15] =
                    oacc[nt][reg];
        lds_barrier();
        #pragma unroll
        for (int ii = 0; ii < 2; ++ii) {
            int rr = w * 8 + ii * 4 + (lane >> 4);
            int c4 = lane & 15;
            *(float4*)(Ob + (size_t)(R0 + rr) * DD + c4 * 4) =
                *(const float4*)&slab[rr * SLW + c4 * 4];
        }
        lds_barrier();   // LDS free for next sweep
    }
}

extern "C" void kernel_launch(void* const* d_in, const int* in_sizes, int n_in,
                              void* d_out, int out_size, void* d_ws, size_t ws_size,
                              hipStream_t stream)
{
    const float* q  = (const float*)d_in[0];
    const float* k  = (const float*)d_in[1];
    const float* v  = (const float*)d_in[2];
    const float* mk = (const float*)d_in[3];
    const int*   mn = (const int*)d_in[4];
    float* out = (float*)d_out;

    const size_t nElem = (size_t)NB * NH * SL * DD;   // 4,194,304
    unsigned short* Qb = (unsigned short*)d_ws;
    unsigned short* Kp = Qb + nElem;
    unsigned short* Vp = Kp + nElem;

    const int n4 = (int)(nElem / 4);
    // Q pre-scaled by (1/8)*log2(e): QK^T lands directly in exp2 domain.
    cvt_bf16<<<n4 / 256, 256, 0, stream>>>(q, Qb, n4, 0.125f * 1.44269504f);
    cvt_bf16<<<n4 / 256, 256, 0, stream>>>(k, Kp, n4, 1.0f);
    transpose_v<<<NB * NH * (SL / 64), 256, 0, stream>>>(v, Vp);

    // 1024 blocks: 8 XCD x 4 bh x 32 fold-pairs. Uniform work per block.
    attn_mfma<<<1024, NT, 0, stream>>>(Qb, Kp, Vp, mk, mn, out);
}